// Round 7
// baseline (13600.710 us; speedup 1.0000x reference)
//
#include <hip/hip_runtime.h>
#include <math.h>

// Problem dims
#define B_  32
#define S_  256
#define I_  256
#define H_  512
#define N_  128
#define C_  64
#define O_  256
#define P_  268          // 4*C + 12
#define K_  832          // I + C + H
#define HB  (H_*B_)      // 16384
#define EPSX 1e-8f
#define NBLK 256

// Workspace layout (float offsets). Total ~7.28M floats = 29.1 MB.
#define OFF_XT   0
#define SZ_XT    (S_*I_*B_)                 // x transposed [t][k][b]
#define OFF_HA   (OFF_XT + SZ_XT)
#define SZ_HA    ((S_+1)*H_*B_)             // h history [t][k][b]
#define OFF_RA   (OFF_HA + SZ_HA)
#define SZ_RA    ((S_+1)*C_*B_)             // r history [t][k][b]
#define OFF_CT   (OFF_RA + SZ_RA)
#define SZ_CT    (H_*B_)                    // LSTM cell state (block-private)
#define OFF_M    (OFF_CT + SZ_CT)
#define SZ_M     (B_*N_*C_)                 // memory [b][n][c] (block-private)
#define OFF_WR   (OFF_M + SZ_M)
#define SZ_W     (B_*N_)                    // unused (layout stability)
#define OFF_WW   (OFF_WR + SZ_W)
#define OFF_BAR  (OFF_WW + SZ_W)
#define SZ_BAR   8192                       // arrive[256] + release[256], 64B-strided
#define OFF_RF   (OFF_BAR + SZ_BAR)
#define SZ_RF    4096                       // r-flags: 256 consumer lines x 16 words
#define OFF_WOT  (OFF_RF + SZ_RF)
#define SZ_WOT   ((H_+C_)*O_)               // W_out transposed [k][o]

__device__ __forceinline__ float sigm(float x) { return 1.f / (1.f + expf(-x)); }
__device__ __forceinline__ float splus(float x) {
    return fmaxf(x, 0.f) + log1pf(expf(-fabsf(x)));  // stable softplus
}
__device__ __forceinline__ float wave_max(float v) {
    #pragma unroll
    for (int s = 1; s < 64; s <<= 1) v = fmaxf(v, __shfl_xor(v, s, 64));
    return v;
}
__device__ __forceinline__ float wave_sum(float v) {
    #pragma unroll
    for (int s = 1; s < 64; s <<= 1) v += __shfl_xor(v, s, 64);
    return v;
}

// ---- fence-free, contention-free grid barrier (round-6, validated) -------
//   arrive[bi]  @ bar[bi*16]        : writer=block bi, reader=master lane bi
//   release[bi] @ bar[4096 + bi*16] : writer=master lane bi, reader=block bi
__device__ __forceinline__ void gbar(unsigned* bar, int bi, int tid, unsigned seq)
{
    __syncthreads();
    if (bi == NBLK - 1) {
        if (tid < NBLK - 1) {
            while (__hip_atomic_load(&bar[tid * 16], __ATOMIC_RELAXED,
                                     __HIP_MEMORY_SCOPE_AGENT) < seq)
                __builtin_amdgcn_s_sleep(1);
        }
        __syncthreads();
        if (tid < NBLK)
            __hip_atomic_store(&bar[4096 + tid * 16], seq, __ATOMIC_RELAXED,
                               __HIP_MEMORY_SCOPE_AGENT);
        __syncthreads();
    } else {
        if (tid == 0) {
            asm volatile("s_waitcnt vmcnt(0) lgkmcnt(0)" ::: "memory");
            __hip_atomic_store(&bar[bi * 16], seq, __ATOMIC_RELAXED,
                               __HIP_MEMORY_SCOPE_AGENT);
            while (__hip_atomic_load(&bar[4096 + bi * 16], __ATOMIC_RELAXED,
                                     __HIP_MEMORY_SCOPE_AGENT) < seq)
                __builtin_amdgcn_s_sleep(1);
        }
        __syncthreads();
    }
}

// ---------------- prep: transpose x & W_out, init state ----------------
__global__ __launch_bounds__(256)
void prep_kernel(const float* __restrict__ x, const float* __restrict__ Wout,
                 float* __restrict__ ws)
{
    int g = blockIdx.x * 256 + threadIdx.x;
    if (g < SZ_XT) {                       // xT[t][k][b] = x[b][t][k]
        int b = g & 31, k = (g >> 5) & 255, t = g >> 13;
        ws[OFF_XT + g] = x[b * (S_*I_) + t * I_ + k];
        return;
    }
    g -= SZ_XT;
    if (g < SZ_WOT) {                      // WoT[k][o] = W_out[o][k]
        int o = g & 255, k = g >> 8;
        ws[OFF_WOT + g] = Wout[o * (H_ + C_) + k];
        return;
    }
    g -= SZ_WOT;
    if (g < HB)      { ws[OFF_HA + g] = 0.f;   return; }   // h slot 0
    g -= HB;
    if (g < C_*B_)   { ws[OFF_RA + g] = 0.f;   return; }   // r slot 0
    g -= C_*B_;
    if (g < SZ_CT)   { ws[OFF_CT + g] = 0.f;   return; }   // c
    g -= SZ_CT;
    if (g < SZ_M)    { ws[OFF_M  + g] = 0.01f; return; }   // M
    g -= SZ_M;
    if (g < 2*SZ_W)  { ws[OFF_WR + g] = 0.f;   return; }   // unused slots
    g -= 2*SZ_W;
    if (g < SZ_BAR)  { ws[OFF_BAR + g] = 0.f;  return; }   // barrier slots
    g -= SZ_BAR;
    if (g < SZ_RF)   { ws[OFF_RF + g] = 0.f;   return; }   // r-flag lines
}

// ---------------- persistent sequential loop -------------------------------
// 256 blocks x 512 threads, 1 block/CU, ONE barrier per step.
// Step t: P1 (x-part, h-part, wait per-consumer r-flag line, r-part) ->
// publish h[t+1] -> gbar -> blocks 0..31 run phase B(t) for batch bi and
// write r(t+1) + flags. Phase B(t) overlaps the other blocks' P1(t+1).
__global__ __launch_bounds__(512)
void ntm_loop(const float* __restrict__ Wih, const float* __restrict__ Whh,
              const float* __restrict__ bl,  const float* __restrict__ Whead,
              const float* __restrict__ bhead, float* __restrict__ ws)
{
    float* xT  = ws + OFF_XT;
    float* hA  = ws + OFF_HA;
    float* rA  = ws + OFF_RA;
    float* cT  = ws + OFF_CT;
    float* Mem = ws + OFF_M;
    unsigned* bar   = (unsigned*)(ws + OFF_BAR);
    unsigned* rflag = (unsigned*)(ws + OFF_RF);

    __shared__ float Wt[K_ * 18];     // gate rows transposed, stride 18
    __shared__ float p_lds[P_];
    __shared__ float sbuf[8];
    __shared__ float wtmp[128];
    __shared__ float wldsR[128];      // persistent w_r (blocks 0..31)
    __shared__ float wldsW[128];      // persistent w_w
    __shared__ float h_lds[H_];       // phase-B h staging

    const int tid = threadIdx.x;
    const int bi  = blockIdx.x;
    const int ug  = bi >> 1;
    const int bh  = bi & 1;

    // Load this block's 16 gate rows into LDS (once per launch).
    for (int idx = tid; idx < K_ * 16; idx += 512) {
        int rl = idx & 15, k = idx >> 4;
        int row = (rl & 3) * H_ + ug * 4 + (rl >> 2);
        float v = (k < I_ + C_) ? Wih[row * (I_ + C_) + k]
                                : Whh[row * H_ + (k - (I_ + C_))];
        Wt[k * 18 + rl] = v;
    }
    if (tid < N_) {                  // persistent addressing weights, w0 = e0
        wldsR[tid] = (tid == 0) ? 1.f : 0.f;
        wldsW[tid] = (tid == 0) ? 1.f : 0.f;
    }

    const int pair = tid >> 5;        // 0..15
    const int ks   = tid & 31;        // split-K lane
    const int rg   = pair >> 2;       // u_local 0..3
    const int bg   = pair & 3;        // batch quad 0..3
    const int b0   = bh * 16 + bg * 4;

    unsigned seq = 0;

    for (int t = 0; t < S_; ++t) {
        // ------------- P1: gates GEMM + LSTM update -> h[t+1], c -------------
        {
            float acc[4][4] = {{0,0,0,0},{0,0,0,0},{0,0,0,0},{0,0,0,0}};
            const float* xs = xT + (size_t)t * I_ * B_;
            const float* rs = rA + (size_t)t * C_ * B_;
            const float* hs = hA + (size_t)t * HB;
            if (t == 0) __syncthreads();   // cover Wt / wlds staging

            // x-part: k = ks + 32i, i in [0,8)
            #pragma unroll
            for (int i = 0; i < 8; ++i) {
                const int kg = ks + (i << 5);
                const float4 a   = *(const float4*)(xs + kg * B_ + b0);
                const float2 w01 = *(const float2*)&Wt[kg * 18 + (rg << 2)];
                const float2 w23 = *(const float2*)&Wt[kg * 18 + (rg << 2) + 2];
                const float wv[4] = {w01.x, w01.y, w23.x, w23.y};
                const float av[4] = {a.x, a.y, a.z, a.w};
                #pragma unroll
                for (int j = 0; j < 4; ++j)
                    #pragma unroll
                    for (int bb = 0; bb < 4; ++bb)
                        acc[j][bb] += wv[j] * av[bb];
            }
            // h-part: k = I+C + ks + 32i, i in [0,16)
            #pragma unroll
            for (int i = 0; i < 16; ++i) {
                const int kl = ks + (i << 5);
                const int kg = I_ + C_ + kl;
                const float4 a   = *(const float4*)(hs + kl * B_ + b0);
                const float2 w01 = *(const float2*)&Wt[kg * 18 + (rg << 2)];
                const float2 w23 = *(const float2*)&Wt[kg * 18 + (rg << 2) + 2];
                const float wv[4] = {w01.x, w01.y, w23.x, w23.y};
                const float av[4] = {a.x, a.y, a.z, a.w};
                #pragma unroll
                for (int j = 0; j < 4; ++j)
                    #pragma unroll
                    for (int bb = 0; bb < 4; ++bb)
                        acc[j][bb] += wv[j] * av[bb];
            }
            // wait for r(t): poll THIS block's private flag line (16 words,
            // one per producer of our batch half; writers store t+1 at the
            // end of phase B(t); init 0 so t=0 passes immediately)
            if (tid < 16) {
                while (__hip_atomic_load(&rflag[bi * 16 + tid], __ATOMIC_RELAXED,
                                         __HIP_MEMORY_SCOPE_AGENT) < (unsigned)t)
                    __builtin_amdgcn_s_sleep(1);
            }
            __syncthreads();
            // r-part: k = I + ks + 32i, i in [0,2) — plain loads are safe:
            // fresh addresses (never cached pre-publication), flag-gated
            #pragma unroll
            for (int i = 0; i < 2; ++i) {
                const int kl = ks + (i << 5);
                const int kg = I_ + kl;
                const float4 a   = *(const float4*)(rs + kl * B_ + b0);
                const float2 w01 = *(const float2*)&Wt[kg * 18 + (rg << 2)];
                const float2 w23 = *(const float2*)&Wt[kg * 18 + (rg << 2) + 2];
                const float wv[4] = {w01.x, w01.y, w23.x, w23.y};
                const float av[4] = {a.x, a.y, a.z, a.w};
                #pragma unroll
                for (int j = 0; j < 4; ++j)
                    #pragma unroll
                    for (int bb = 0; bb < 4; ++bb)
                        acc[j][bb] += wv[j] * av[bb];
            }
            // split-K butterfly over 32 lanes
            #pragma unroll
            for (int j = 0; j < 4; ++j)
                #pragma unroll
                for (int bb = 0; bb < 4; ++bb) {
                    float v = acc[j][bb];
                    v += __shfl_xor(v, 16, 64);
                    v += __shfl_xor(v, 8, 64);
                    v += __shfl_xor(v, 4, 64);
                    v += __shfl_xor(v, 2, 64);
                    v += __shfl_xor(v, 1, 64);
                    acc[j][bb] = v;
                }
            if (ks == 0) {
                const int unit = ug * 4 + rg;
                #pragma unroll
                for (int bb = 0; bb < 4; ++bb) {
                    const int b = b0 + bb;
                    float gi = acc[0][bb] + bl[unit];
                    float gf = acc[1][bb] + bl[H_ + unit];
                    float gg = acc[2][bb] + bl[2 * H_ + unit];
                    float go = acc[3][bb] + bl[3 * H_ + unit];
                    float cN = sigm(gf) * cT[unit * B_ + b] + sigm(gi) * tanhf(gg);
                    float hN = sigm(go) * tanhf(cN);
                    cT[unit * B_ + b] = cN;   // private
                    __hip_atomic_store(&hA[(size_t)(t + 1) * HB + unit * B_ + b],
                                       hN, __ATOMIC_RELAXED,
                                       __HIP_MEMORY_SCOPE_AGENT);
                }
            }
        }
        gbar(bar, bi, tid, ++seq);    // the ONLY grid sync per step

        // ---- Phase B (blocks 0..31): head GEMM + addressing + write + read ----
        // Overlaps the other 224 blocks' P1(t+1) x/h work.
        if (bi < B_) {
            const int b = bi;
            float* Mb = Mem + (size_t)b * N_ * C_;
            const float* hs = hA + (size_t)(t + 1) * HB;

            // stage h[:,b] into LDS (agent loads: read coherence point)
            h_lds[tid] = __hip_atomic_load(&hs[tid * B_ + b], __ATOMIC_RELAXED,
                                           __HIP_MEMORY_SCOPE_AGENT);
            __syncthreads();

            // head GEMM: p = W_head @ h + b_head, 2 threads per row (split-K)
            {
                const int sub  = tid & 1;        // k-half
                const int row0 = tid >> 1;       // 0..255
                const float* hb = &h_lds[sub * 256];
                {
                    const float* wrow = Whead + row0 * H_ + sub * 256;
                    float acc = 0.f;
                    #pragma unroll 8
                    for (int k2 = 0; k2 < 256; k2 += 4) {
                        const float4 w4 = *(const float4*)&wrow[k2];
                        acc += w4.x * hb[k2] + w4.y * hb[k2 + 1]
                             + w4.z * hb[k2 + 2] + w4.w * hb[k2 + 3];
                    }
                    acc += __shfl_xor(acc, 1, 64);
                    if (sub == 0) p_lds[row0] = acc + bhead[row0];
                }
                if (row0 < P_ - 256) {           // rows 256..267
                    const int row1 = row0 + 256;
                    const float* wrow = Whead + row1 * H_ + sub * 256;
                    float acc = 0.f;
                    #pragma unroll 8
                    for (int k2 = 0; k2 < 256; k2 += 4) {
                        const float4 w4 = *(const float4*)&wrow[k2];
                        acc += w4.x * hb[k2] + w4.y * hb[k2 + 1]
                             + w4.z * hb[k2 + 2] + w4.w * hb[k2 + 3];
                    }
                    acc += __shfl_xor(acc, 1, 64);
                    if (sub == 0) p_lds[row1] = acc + bhead[row1];
                }
            }
            __syncthreads();

            // addressing: pass 0 read head (params at 0), pass 1 write head (70)
            for (int pass = 0; pass < 2; ++pass) {
                const int o = pass ? 70 : 0;
                float z = 0.f, beta = 0.f, gate = 0.f, s0 = 0.f, s1 = 0.f,
                      s2 = 0.f, gamma = 1.f;
                if (tid < N_) {
                    beta  = splus(p_lds[o + 64]);
                    gate  = sigm(p_lds[o + 65]);
                    float sa = p_lds[o + 66], sbv = p_lds[o + 67], sc = p_lds[o + 68];
                    float sm3 = fmaxf(sa, fmaxf(sbv, sc));
                    float ea = __expf(sa - sm3), eb = __expf(sbv - sm3),
                          ec = __expf(sc - sm3);
                    float es3 = ea + eb + ec;
                    s0 = ea / es3; s1 = eb / es3; s2 = ec / es3;
                    gamma = 1.f + splus(p_lds[o + 69]);
                    float kk = 0.f;
                    #pragma unroll 8
                    for (int c = 0; c < C_; ++c) { float kv = p_lds[o + c]; kk += kv * kv; }
                    const float knorm = sqrtf(kk) + EPSX;
                    float dot = 0.f, mm = 0.f;
                    #pragma unroll
                    for (int c = 0; c < C_; c += 4) {
                        float4 m4 = *(const float4*)&Mb[tid * C_ + c];
                        dot += m4.x * p_lds[o + c]     + m4.y * p_lds[o + c + 1]
                             + m4.z * p_lds[o + c + 2] + m4.w * p_lds[o + c + 3];
                        mm  += m4.x * m4.x + m4.y * m4.y + m4.z * m4.z + m4.w * m4.w;
                    }
                    z = beta * (dot / ((sqrtf(mm) + EPSX) * knorm));
                }
                // softmax over n=128 via wave shuffles (waves 0,1 fully active)
                float zm = wave_max(z);
                if (tid < N_ && (tid & 63) == 0) sbuf[tid >> 6] = zm;
                __syncthreads();
                const float zmax = fmaxf(sbuf[0], sbuf[1]);
                float ev = (tid < N_) ? __expf(z - zmax) : 0.f;
                float es = wave_sum(ev);
                if (tid < N_ && (tid & 63) == 0) sbuf[2 + (tid >> 6)] = es;
                __syncthreads();
                const float esum = sbuf[2] + sbuf[3];
                if (tid < N_) {
                    float wc = ev / esum;
                    float wprev_v = pass ? wldsW[tid] : wldsR[tid];
                    wtmp[tid] = gate * wc + (1.f - gate) * wprev_v;
                }
                __syncthreads();
                float wp = 0.f;
                if (tid < N_) {
                    float wsft = s0 * wtmp[(tid + 1) & (N_-1)] + s1 * wtmp[tid]
                               + s2 * wtmp[(tid - 1) & (N_-1)];
                    wp = __powf(wsft + EPSX, gamma);
                }
                float ps = wave_sum(wp);
                if (tid < N_ && (tid & 63) == 0) sbuf[4 + (tid >> 6)] = ps;
                __syncthreads();
                const float psum = sbuf[4] + sbuf[5];
                if (tid < N_) {
                    float wn = wp / psum;
                    if (pass) wldsW[tid] = wn; else wldsR[tid] = wn;
                }
                __syncthreads();
            }

            // M = M*(1 - w_w e) + w_w a   (private)
            for (int idx = tid; idx < (N_ * C_) / 4; idx += 512) {
                const int n = idx >> 4;
                const int c = (idx & 15) << 2;
                const float wwn = wldsW[n];
                float4 m4 = *(float4*)&Mb[n * C_ + c];
                m4.x = m4.x * (1.f - wwn * sigm(p_lds[140 + c]))     + wwn * p_lds[204 + c];
                m4.y = m4.y * (1.f - wwn * sigm(p_lds[140 + c + 1])) + wwn * p_lds[204 + c + 1];
                m4.z = m4.z * (1.f - wwn * sigm(p_lds[140 + c + 2])) + wwn * p_lds[204 + c + 2];
                m4.w = m4.w * (1.f - wwn * sigm(p_lds[140 + c + 3])) + wwn * p_lds[204 + c + 3];
                *(float4*)&Mb[n * C_ + c] = m4;
            }
            __syncthreads();

            // r = w_r @ M_new  -> publish to L3
            {
                const int c = tid >> 3, ns = tid & 7;
                float acc = 0.f;
                #pragma unroll
                for (int i = 0; i < 16; ++i) {
                    const int n = ns + 8 * i;
                    acc += wldsR[n] * Mb[n * C_ + c];
                }
                acc += __shfl_xor(acc, 4, 64);
                acc += __shfl_xor(acc, 2, 64);
                acc += __shfl_xor(acc, 1, 64);
                if (ns == 0)
                    __hip_atomic_store(&rA[(size_t)(t + 1) * C_ * B_ + c * B_ + b],
                                       acc, __ATOMIC_RELAXED,
                                       __HIP_MEMORY_SCOPE_AGENT);
            }
            __syncthreads();   // all waves drain their r stores (vmcnt) here

            // flag fan-out: one store per matching-parity consumer block's
            // private line, word (b & 15). 128 lanes, 128 distinct lines.
            if (tid < 128) {
                const int cons = 2 * tid + (b >> 4);   // consumers with bh == b>>4
                __hip_atomic_store(&rflag[cons * 16 + (b & 15)],
                                   (unsigned)(t + 1), __ATOMIC_RELAXED,
                                   __HIP_MEMORY_SCOPE_AGENT);
            }
        }
    }
}

// ---------------- final output GEMM ----------------
__global__ __launch_bounds__(256)
void out_kernel(const float* __restrict__ ws, const float* __restrict__ bout,
                float* __restrict__ out)
{
    __shared__ float actL[(H_ + C_) * 16];   // 36,864 B
    const float* hA  = ws + OFF_HA;
    const float* rA  = ws + OFF_RA;
    const float* WoT = ws + OFF_WOT;
    const int t   = blockIdx.x >> 1;
    const int bh  = blockIdx.x & 1;
    const int tid = threadIdx.x;

    for (int idx = tid; idx < (H_ + C_) * 16; idx += 256) {
        const int k = idx >> 4, bl2 = idx & 15, b = bh * 16 + bl2;
        float v = (k < H_) ? hA[(size_t)(t + 1) * HB + k * B_ + b]
                           : rA[(size_t)(t + 1) * C_ * B_ + (k - H_) * B_ + b];
        actL[k * 16 + bl2] = v;
    }
    __syncthreads();

    const int ot = tid & 63, bt = tid >> 6;
    const int o0 = ot * 4, bl0 = bt * 4;
    float acc[4][4] = {{0,0,0,0},{0,0,0,0},{0,0,0,0},{0,0,0,0}};
    for (int k = 0; k < H_ + C_; ++k) {
        const float4 w4 = *(const float4*)&WoT[k * O_ + o0];
        const float4 a4 = *(const float4*)&actL[k * 16 + bl0];
        const float wv[4] = {w4.x, w4.y, w4.z, w4.w};
        const float av[4] = {a4.x, a4.y, a4.z, a4.w};
        #pragma unroll
        for (int j = 0; j < 4; ++j)
            #pragma unroll
            for (int bb = 0; bb < 4; ++bb)
                acc[j][bb] += wv[j] * av[bb];
    }
    const float4 bo = *(const float4*)&bout[o0];
    #pragma unroll
    for (int bb = 0; bb < 4; ++bb) {
        const int b = bh * 16 + bl0 + bb;
        float4 res;
        res.x = acc[0][bb] + bo.x;
        res.y = acc[1][bb] + bo.y;
        res.z = acc[2][bb] + bo.z;
        res.w = acc[3][bb] + bo.w;
        *(float4*)&out[((size_t)b * S_ + t) * O_ + o0] = res;
    }
}

extern "C" void kernel_launch(void* const* d_in, const int* in_sizes, int n_in,
                              void* d_out, int out_size, void* d_ws, size_t ws_size,
                              hipStream_t stream)
{
    const float* x    = (const float*)d_in[0];
    const float* Wih  = (const float*)d_in[1];
    const float* Whh  = (const float*)d_in[2];
    const float* bl   = (const float*)d_in[3];
    const float* Whd  = (const float*)d_in[4];
    const float* bhd  = (const float*)d_in[5];
    const float* Wout = (const float*)d_in[6];
    const float* bout = (const float*)d_in[7];
    float* ws  = (float*)d_ws;    // needs 29.2 MB
    float* out = (float*)d_out;

    prep_kernel<<<10008, 256, 0, stream>>>(x, Wout, ws);

    void* args[] = { (void*)&Wih, (void*)&Whh, (void*)&bl,
                     (void*)&Whd, (void*)&bhd, (void*)&ws };
    (void)hipLaunchCooperativeKernel((void*)ntm_loop, dim3(256), dim3(512), args, 0, stream);

    out_kernel<<<512, 256, 0, stream>>>(ws, bout, out);
}

// Round 9
// 12187.045 us; speedup vs baseline: 1.1160x; 1.1160x over previous
//
#include <hip/hip_runtime.h>
#include <math.h>

// Problem dims
#define B_  32
#define S_  256
#define I_  256
#define H_  512
#define N_  128
#define C_  64
#define O_  256
#define P_  268          // 4*C + 12
#define K_  832          // I + C + H
#define HB  (H_*B_)      // 16384
#define EPSX 1e-8f
#define NBLK 256

// Workspace layout (float offsets). Total ~7.28M floats = 29.1 MB.
#define OFF_XT   0
#define SZ_XT    (S_*I_*B_)                 // x transposed [t][k][b]
#define OFF_HA   (OFF_XT + SZ_XT)
#define SZ_HA    ((S_+1)*H_*B_)             // h history [t][k][b]
#define OFF_RA   (OFF_HA + SZ_HA)
#define SZ_RA    ((S_+1)*C_*B_)             // r history [t][k][b]
#define OFF_CT   (OFF_RA + SZ_RA)
#define SZ_CT    (H_*B_)                    // LSTM cell state (block-private)
#define OFF_M    (OFF_CT + SZ_CT)
#define SZ_M     (B_*N_*C_)                 // memory [b][n][c] (block-private)
#define OFF_WR   (OFF_M + SZ_M)
#define SZ_W     (B_*N_)                    // unused (layout stability)
#define OFF_WW   (OFF_WR + SZ_W)
#define OFF_BAR  (OFF_WW + SZ_W)
#define SZ_BAR   12800                      // flag lines (see PA_/AG1_/HD_/RF_)
#define OFF_WOT  (OFF_BAR + SZ_BAR)
#define SZ_WOT   ((H_+C_)*O_)               // W_out transposed [k][o]

// Flag word-offsets inside BAR (all on private 64B lines, 1 writer/1 poller):
//  PA_(i)  : producer i arrived (h published)     writer=block i, reader=agg
//  AG1_(j) : aggregator j's group done            writer=block 224+j, reader=255
//  HD_(i)  : h done, per-consumer broadcast       writer=block 255, reader=block i
//  RF_(i,w): r ready, per-consumer line, word w   writer=phaseB block, reader=block i
#define PA_(i)   ((i)*16)
#define AG1_(j)  (4096 + (j)*16)
#define HD_(i)   (4608 + (i)*16)
#define RF_(i,w) (8704 + (i)*16 + (w))

__device__ __forceinline__ float sigm(float x) { return 1.f / (1.f + expf(-x)); }
__device__ __forceinline__ float splus(float x) {
    return fmaxf(x, 0.f) + log1pf(expf(-fabsf(x)));  // stable softplus
}
__device__ __forceinline__ float wave_max(float v) {
    #pragma unroll
    for (int s = 1; s < 64; s <<= 1) v = fmaxf(v, __shfl_xor(v, s, 64));
    return v;
}
__device__ __forceinline__ float wave_sum(float v) {
    #pragma unroll
    for (int s = 1; s < 64; s <<= 1) v += __shfl_xor(v, s, 64);
    return v;
}

// poll a private flag word until >= tgt, with sleep backoff (keeps L3 cool).
// s_sleep arg must be a compile-time constant -> branch to constant calls.
__device__ __forceinline__ void gwait(unsigned* p, unsigned tgt) {
    int it = 0;
    while (__hip_atomic_load(p, __ATOMIC_RELAXED, __HIP_MEMORY_SCOPE_AGENT) < tgt) {
        if (it < 4) __builtin_amdgcn_s_sleep(1);
        else        __builtin_amdgcn_s_sleep(8);
        ++it;
    }
}
__device__ __forceinline__ void gpost(unsigned* p, unsigned v) {
    __hip_atomic_store(p, v, __ATOMIC_RELAXED, __HIP_MEMORY_SCOPE_AGENT);
}

// ---------------- prep: transpose x & W_out, init state ----------------
__global__ __launch_bounds__(256)
void prep_kernel(const float* __restrict__ x, const float* __restrict__ Wout,
                 float* __restrict__ ws)
{
    int g = blockIdx.x * 256 + threadIdx.x;
    if (g < SZ_XT) {                       // xT[t][k][b] = x[b][t][k]
        int b = g & 31, k = (g >> 5) & 255, t = g >> 13;
        ws[OFF_XT + g] = x[b * (S_*I_) + t * I_ + k];
        return;
    }
    g -= SZ_XT;
    if (g < SZ_WOT) {                      // WoT[k][o] = W_out[o][k]
        int o = g & 255, k = g >> 8;
        ws[OFF_WOT + g] = Wout[o * (H_ + C_) + k];
        return;
    }
    g -= SZ_WOT;
    if (g < HB)      { ws[OFF_HA + g] = 0.f;   return; }   // h slot 0
    g -= HB;
    if (g < C_*B_)   { ws[OFF_RA + g] = 0.f;   return; }   // r slot 0
    g -= C_*B_;
    if (g < SZ_CT)   { ws[OFF_CT + g] = 0.f;   return; }   // c
    g -= SZ_CT;
    if (g < SZ_M)    { ws[OFF_M  + g] = 0.01f; return; }   // M
    g -= SZ_M;
    if (g < 2*SZ_W)  { ws[OFF_WR + g] = 0.f;   return; }   // unused slots
    g -= 2*SZ_W;
    if (g < SZ_BAR)  { ws[OFF_BAR + g] = 0.f;  return; }   // flag lines
}

// ---------------- persistent barrier-free data-flow loop --------------------
// 256 blocks x 512 threads, 1 block/CU, NO grid barrier.
// Block bi: ug = bi>>1 owns units [4ug,4ug+4), bh = bi&1 owns batches
// [16bh,16bh+16). Blocks 0..31: full phase B for batch bi (M,w in LDS/private).
// Blocks 224..239: level-1 h-aggregators; block 255: level-2 + hdone fan-out.
__global__ __launch_bounds__(512)
void ntm_loop(const float* __restrict__ Wih, const float* __restrict__ Whh,
              const float* __restrict__ bl,  const float* __restrict__ Whead,
              const float* __restrict__ bhead, float* __restrict__ ws)
{
    float* xT  = ws + OFF_XT;
    float* hA  = ws + OFF_HA;
    float* rA  = ws + OFF_RA;
    float* cT  = ws + OFF_CT;
    float* Mem = ws + OFF_M;
    unsigned* barr = (unsigned*)(ws + OFF_BAR);

    __shared__ float Wt[K_ * 18];     // gate rows transposed, stride 18
    __shared__ float p_lds[P_];
    __shared__ float sbuf[8];
    __shared__ float wtmp[128];
    __shared__ float wldsR[128];      // persistent w_r (blocks 0..31)
    __shared__ float wldsW[128];      // persistent w_w
    __shared__ float h_lds[H_];       // phase-B h staging

    const int tid = threadIdx.x;
    const int bi  = blockIdx.x;
    const int ug  = bi >> 1;
    const int bh  = bi & 1;

    // Load this block's 16 gate rows into LDS (once per launch).
    for (int idx = tid; idx < K_ * 16; idx += 512) {
        int rl = idx & 15, k = idx >> 4;
        int row = (rl & 3) * H_ + ug * 4 + (rl >> 2);
        float v = (k < I_ + C_) ? Wih[row * (I_ + C_) + k]
                                : Whh[row * H_ + (k - (I_ + C_))];
        Wt[k * 18 + rl] = v;
    }
    if (tid < N_) {                  // persistent addressing weights, w0 = e0
        wldsR[tid] = (tid == 0) ? 1.f : 0.f;
        wldsW[tid] = (tid == 0) ? 1.f : 0.f;
    }

    const int pair = tid >> 5;        // 0..15
    const int ks   = tid & 31;        // split-K lane
    const int rg   = pair >> 2;       // u_local 0..3
    const int bg   = pair & 3;        // batch quad 0..3
    const int b0   = bh * 16 + bg * 4;

    for (int t = 0; t < S_; ++t) {
        // ------------- P1: gates GEMM + LSTM update -> h[t+1], c -------------
        {
            float acc[4][4] = {{0,0,0,0},{0,0,0,0},{0,0,0,0},{0,0,0,0}};
            const float* xs = xT + (size_t)t * I_ * B_;
            const float* rs = rA + (size_t)t * C_ * B_;
            const float* hs = hA + (size_t)t * HB;
            if (t == 0) __syncthreads();   // cover Wt / wlds staging

            // x-part (no deps): k = ks + 32i, i in [0,8)
            #pragma unroll
            for (int i = 0; i < 8; ++i) {
                const int kg = ks + (i << 5);
                const float4 a   = *(const float4*)(xs + kg * B_ + b0);
                const float2 w01 = *(const float2*)&Wt[kg * 18 + (rg << 2)];
                const float2 w23 = *(const float2*)&Wt[kg * 18 + (rg << 2) + 2];
                const float wv[4] = {w01.x, w01.y, w23.x, w23.y};
                const float av[4] = {a.x, a.y, a.z, a.w};
                #pragma unroll
                for (int j = 0; j < 4; ++j)
                    #pragma unroll
                    for (int bb = 0; bb < 4; ++bb)
                        acc[j][bb] += wv[j] * av[bb];
            }
            // gate: h(t) fully published (hdone private line >= t; init 0)
            if (tid == 0) gwait(&barr[HD_(bi)], (unsigned)t);
            __syncthreads();
            // h-part (plain cached loads — flag-gated): i in [0,16)
            #pragma unroll
            for (int i = 0; i < 16; ++i) {
                const int kl = ks + (i << 5);
                const int kg = I_ + C_ + kl;
                const float4 a   = *(const float4*)(hs + kl * B_ + b0);
                const float2 w01 = *(const float2*)&Wt[kg * 18 + (rg << 2)];
                const float2 w23 = *(const float2*)&Wt[kg * 18 + (rg << 2) + 2];
                const float wv[4] = {w01.x, w01.y, w23.x, w23.y};
                const float av[4] = {a.x, a.y, a.z, a.w};
                #pragma unroll
                for (int j = 0; j < 4; ++j)
                    #pragma unroll
                    for (int bb = 0; bb < 4; ++bb)
                        acc[j][bb] += wv[j] * av[bb];
            }
            // gate: r(t) from our 16 producers (private line, 16 words; init 0)
            if (tid < 16) gwait(&barr[RF_(bi, tid)], (unsigned)t);
            __syncthreads();
            // r-part (plain loads — flag-gated): i in [0,2)
            #pragma unroll
            for (int i = 0; i < 2; ++i) {
                const int kl = ks + (i << 5);
                const int kg = I_ + kl;
                const float4 a   = *(const float4*)(rs + kl * B_ + b0);
                const float2 w01 = *(const float2*)&Wt[kg * 18 + (rg << 2)];
                const float2 w23 = *(const float2*)&Wt[kg * 18 + (rg << 2) + 2];
                const float wv[4] = {w01.x, w01.y, w23.x, w23.y};
                const float av[4] = {a.x, a.y, a.z, a.w};
                #pragma unroll
                for (int j = 0; j < 4; ++j)
                    #pragma unroll
                    for (int bb = 0; bb < 4; ++bb)
                        acc[j][bb] += wv[j] * av[bb];
            }
            // split-K butterfly over 32 lanes
            #pragma unroll
            for (int j = 0; j < 4; ++j)
                #pragma unroll
                for (int bb = 0; bb < 4; ++bb) {
                    float v = acc[j][bb];
                    v += __shfl_xor(v, 16, 64);
                    v += __shfl_xor(v, 8, 64);
                    v += __shfl_xor(v, 4, 64);
                    v += __shfl_xor(v, 2, 64);
                    v += __shfl_xor(v, 1, 64);
                    acc[j][bb] = v;
                }
            if (ks == 0) {
                const int unit = ug * 4 + rg;
                #pragma unroll
                for (int bb = 0; bb < 4; ++bb) {
                    const int b = b0 + bb;
                    float gi = acc[0][bb] + bl[unit];
                    float gf = acc[1][bb] + bl[H_ + unit];
                    float gg = acc[2][bb] + bl[2 * H_ + unit];
                    float go = acc[3][bb] + bl[3 * H_ + unit];
                    float cN = sigm(gf) * cT[unit * B_ + b] + sigm(gi) * tanhf(gg);
                    float hN = sigm(go) * tanhf(cN);
                    cT[unit * B_ + b] = cN;   // private
                    __hip_atomic_store(&hA[(size_t)(t + 1) * HB + unit * B_ + b],
                                       hN, __ATOMIC_RELAXED,
                                       __HIP_MEMORY_SCOPE_AGENT);
                }
            }
        }
        __syncthreads();                    // each wave drains vmcnt pre-post
        if (tid == 0) gpost(&barr[PA_(bi)], (unsigned)(t + 1));   // h published
        asm volatile("" ::: "memory");

        // ---- h-aggregation tree (runs every step, off to the side) ----
        if (bi >= 224 && bi < 240) {        // level-1: 16 producers each
            if (tid < 16) gwait(&barr[PA_((bi - 224) * 16 + tid)], (unsigned)(t + 1));
            // wave 0 reconverged here
            if (tid == 0) gpost(&barr[AG1_(bi - 224)], (unsigned)(t + 1));
        }
        if (bi == NBLK - 1) {               // level-2 + fan-out
            if (tid < 16) gwait(&barr[AG1_(tid)], (unsigned)(t + 1));
            __syncthreads();
            if (tid < NBLK) gpost(&barr[HD_(tid)], (unsigned)(t + 1));
        }

        // ---- Phase B (blocks 0..31): head GEMM + addressing + write + read ----
        if (bi < B_) {
            const int b = bi;
            float* Mb = Mem + (size_t)b * N_ * C_;
            const float* hs = hA + (size_t)(t + 1) * HB;

            // gate: h(t+1) complete, then plain column loads
            if (tid == 0) gwait(&barr[HD_(bi)], (unsigned)(t + 1));
            __syncthreads();
            h_lds[tid] = hs[tid * B_ + b];
            __syncthreads();

            // head GEMM: p = W_head @ h + b_head, 2 threads per row (split-K)
            {
                const int sub  = tid & 1;        // k-half
                const int row0 = tid >> 1;       // 0..255
                const float* hb = &h_lds[sub * 256];
                {
                    const float* wrow = Whead + row0 * H_ + sub * 256;
                    float acc = 0.f;
                    #pragma unroll 8
                    for (int k2 = 0; k2 < 256; k2 += 4) {
                        const float4 w4 = *(const float4*)&wrow[k2];
                        acc += w4.x * hb[k2] + w4.y * hb[k2 + 1]
                             + w4.z * hb[k2 + 2] + w4.w * hb[k2 + 3];
                    }
                    acc += __shfl_xor(acc, 1, 64);
                    if (sub == 0) p_lds[row0] = acc + bhead[row0];
                }
                if (row0 < P_ - 256) {           // rows 256..267
                    const int row1 = row0 + 256;
                    const float* wrow = Whead + row1 * H_ + sub * 256;
                    float acc = 0.f;
                    #pragma unroll 8
                    for (int k2 = 0; k2 < 256; k2 += 4) {
                        const float4 w4 = *(const float4*)&wrow[k2];
                        acc += w4.x * hb[k2] + w4.y * hb[k2 + 1]
                             + w4.z * hb[k2 + 2] + w4.w * hb[k2 + 3];
                    }
                    acc += __shfl_xor(acc, 1, 64);
                    if (sub == 0) p_lds[row1] = acc + bhead[row1];
                }
            }
            __syncthreads();

            // addressing: pass 0 read head (params at 0), pass 1 write head (70)
            for (int pass = 0; pass < 2; ++pass) {
                const int o = pass ? 70 : 0;
                float z = 0.f, beta = 0.f, gate = 0.f, s0 = 0.f, s1 = 0.f,
                      s2 = 0.f, gamma = 1.f;
                if (tid < N_) {
                    beta  = splus(p_lds[o + 64]);
                    gate  = sigm(p_lds[o + 65]);
                    float sa = p_lds[o + 66], sbv = p_lds[o + 67], sc = p_lds[o + 68];
                    float sm3 = fmaxf(sa, fmaxf(sbv, sc));
                    float ea = __expf(sa - sm3), eb = __expf(sbv - sm3),
                          ec = __expf(sc - sm3);
                    float es3 = ea + eb + ec;
                    s0 = ea / es3; s1 = eb / es3; s2 = ec / es3;
                    gamma = 1.f + splus(p_lds[o + 69]);
                    float kk = 0.f;
                    #pragma unroll 8
                    for (int c = 0; c < C_; ++c) { float kv = p_lds[o + c]; kk += kv * kv; }
                    const float knorm = sqrtf(kk) + EPSX;
                    float dot = 0.f, mm = 0.f;
                    #pragma unroll
                    for (int c = 0; c < C_; c += 4) {
                        float4 m4 = *(const float4*)&Mb[tid * C_ + c];
                        dot += m4.x * p_lds[o + c]     + m4.y * p_lds[o + c + 1]
                             + m4.z * p_lds[o + c + 2] + m4.w * p_lds[o + c + 3];
                        mm  += m4.x * m4.x + m4.y * m4.y + m4.z * m4.z + m4.w * m4.w;
                    }
                    z = beta * (dot / ((sqrtf(mm) + EPSX) * knorm));
                }
                // softmax over n=128 via wave shuffles
                float zm = wave_max(z);
                if (tid < N_ && (tid & 63) == 0) sbuf[tid >> 6] = zm;
                __syncthreads();
                const float zmax = fmaxf(sbuf[0], sbuf[1]);
                float ev = (tid < N_) ? __expf(z - zmax) : 0.f;
                float es = wave_sum(ev);
                if (tid < N_ && (tid & 63) == 0) sbuf[2 + (tid >> 6)] = es;
                __syncthreads();
                const float esum = sbuf[2] + sbuf[3];
                if (tid < N_) {
                    float wc = ev / esum;
                    float wprev_v = pass ? wldsW[tid] : wldsR[tid];
                    wtmp[tid] = gate * wc + (1.f - gate) * wprev_v;
                }
                __syncthreads();
                float wp = 0.f;
                if (tid < N_) {
                    float wsft = s0 * wtmp[(tid + 1) & (N_-1)] + s1 * wtmp[tid]
                               + s2 * wtmp[(tid - 1) & (N_-1)];
                    wp = __powf(wsft + EPSX, gamma);
                }
                float ps = wave_sum(wp);
                if (tid < N_ && (tid & 63) == 0) sbuf[4 + (tid >> 6)] = ps;
                __syncthreads();
                const float psum = sbuf[4] + sbuf[5];
                if (tid < N_) {
                    float wn = wp / psum;
                    if (pass) wldsW[tid] = wn; else wldsR[tid] = wn;
                }
                __syncthreads();
            }

            // M = M*(1 - w_w e) + w_w a   (private)
            for (int idx = tid; idx < (N_ * C_) / 4; idx += 512) {
                const int n = idx >> 4;
                const int c = (idx & 15) << 2;
                const float wwn = wldsW[n];
                float4 m4 = *(float4*)&Mb[n * C_ + c];
                m4.x = m4.x * (1.f - wwn * sigm(p_lds[140 + c]))     + wwn * p_lds[204 + c];
                m4.y = m4.y * (1.f - wwn * sigm(p_lds[140 + c + 1])) + wwn * p_lds[204 + c + 1];
                m4.z = m4.z * (1.f - wwn * sigm(p_lds[140 + c + 2])) + wwn * p_lds[204 + c + 2];
                m4.w = m4.w * (1.f - wwn * sigm(p_lds[140 + c + 3])) + wwn * p_lds[204 + c + 3];
                *(float4*)&Mb[n * C_ + c] = m4;
            }
            __syncthreads();

            // r = w_r @ M_new  -> publish to L3
            {
                const int c = tid >> 3, ns = tid & 7;
                float acc = 0.f;
                #pragma unroll
                for (int i = 0; i < 16; ++i) {
                    const int n = ns + 8 * i;
                    acc += wldsR[n] * Mb[n * C_ + c];
                }
                acc += __shfl_xor(acc, 4, 64);
                acc += __shfl_xor(acc, 2, 64);
                acc += __shfl_xor(acc, 1, 64);
                if (ns == 0)
                    __hip_atomic_store(&rA[(size_t)(t + 1) * C_ * B_ + c * B_ + b],
                                       acc, __ATOMIC_RELAXED,
                                       __HIP_MEMORY_SCOPE_AGENT);
            }
            __syncthreads();   // all waves drain r stores (vmcnt)

            // r-flag fan-out: one store per matching-parity consumer's private
            // line, word (b & 15). 128 lanes -> 128 distinct lines.
            if (tid < 128) {
                const int cons = 2 * tid + (b >> 4);
                gpost(&barr[RF_(cons, b & 15)], (unsigned)(t + 1));
            }
        }
    }
}

// ---------------- final output GEMM ----------------
__global__ __launch_bounds__(256)
void out_kernel(const float* __restrict__ ws, const float* __restrict__ bout,
                float* __restrict__ out)
{
    __shared__ float actL[(H_ + C_) * 16];   // 36,864 B
    const float* hA  = ws + OFF_HA;
    const float* rA  = ws + OFF_RA;
    const float* WoT = ws + OFF_WOT;
    const int t   = blockIdx.x >> 1;
    const int bh  = blockIdx.x & 1;
    const int tid = threadIdx.x;

    for (int idx = tid; idx < (H_ + C_) * 16; idx += 256) {
        const int k = idx >> 4, bl2 = idx & 15, b = bh * 16 + bl2;
        float v = (k < H_) ? hA[(size_t)(t + 1) * HB + k * B_ + b]
                           : rA[(size_t)(t + 1) * C_ * B_ + (k - H_) * B_ + b];
        actL[k * 16 + bl2] = v;
    }
    __syncthreads();

    const int ot = tid & 63, bt = tid >> 6;
    const int o0 = ot * 4, bl0 = bt * 4;
    float acc[4][4] = {{0,0,0,0},{0,0,0,0},{0,0,0,0},{0,0,0,0}};
    for (int k = 0; k < H_ + C_; ++k) {
        const float4 w4 = *(const float4*)&WoT[k * O_ + o0];
        const float4 a4 = *(const float4*)&actL[k * 16 + bl0];
        const float wv[4] = {w4.x, w4.y, w4.z, w4.w};
        const float av[4] = {a4.x, a4.y, a4.z, a4.w};
        #pragma unroll
        for (int j = 0; j < 4; ++j)
            #pragma unroll
            for (int bb = 0; bb < 4; ++bb)
                acc[j][bb] += wv[j] * av[bb];
    }
    const float4 bo = *(const float4*)&bout[o0];
    #pragma unroll
    for (int bb = 0; bb < 4; ++bb) {
        const int b = bh * 16 + bl0 + bb;
        float4 res;
        res.x = acc[0][bb] + bo.x;
        res.y = acc[1][bb] + bo.y;
        res.z = acc[2][bb] + bo.z;
        res.w = acc[3][bb] + bo.w;
        *(float4*)&out[((size_t)b * S_ + t) * O_ + o0] = res;
    }
}

extern "C" void kernel_launch(void* const* d_in, const int* in_sizes, int n_in,
                              void* d_out, int out_size, void* d_ws, size_t ws_size,
                              hipStream_t stream)
{
    const float* x    = (const float*)d_in[0];
    const float* Wih  = (const float*)d_in[1];
    const float* Whh  = (const float*)d_in[2];
    const float* bl   = (const float*)d_in[3];
    const float* Whd  = (const float*)d_in[4];
    const float* bhd  = (const float*)d_in[5];
    const float* Wout = (const float*)d_in[6];
    const float* bout = (const float*)d_in[7];
    float* ws  = (float*)d_ws;    // needs 29.2 MB
    float* out = (float*)d_out;

    prep_kernel<<<10011, 256, 0, stream>>>(x, Wout, ws);

    void* args[] = { (void*)&Wih, (void*)&Whh, (void*)&bl,
                     (void*)&Whd, (void*)&bhd, (void*)&ws };
    (void)hipLaunchCooperativeKernel((void*)ntm_loop, dim3(256), dim3(512), args, 0, stream);

    out_kernel<<<512, 256, 0, stream>>>(ws, bout, out);
}

// Round 10
// 8640.469 us; speedup vs baseline: 1.5741x; 1.4105x over previous
//
#include <hip/hip_runtime.h>
#include <hip/hip_fp16.h>
#include <math.h>

// Problem dims
#define B_  32
#define S_  256
#define I_  256
#define H_  512
#define N_  128
#define C_  64
#define O_  256
#define P_  268          // 4*C + 12
#define K_  832          // I + C + H
#define HB  (H_*B_)      // 16384
#define EPSX 1e-8f
#define NBLK 256

// Workspace layout (float offsets). Total 7,345,152 floats = 29.4 MB.
#define OFF_XT   0
#define SZ_XT    (S_*I_*B_)                 // x transposed [t][k][b]
#define OFF_HA   (OFF_XT + SZ_XT)
#define SZ_HA    ((S_+1)*H_*B_)             // h history [t][k][b]
#define OFF_RA   (OFF_HA + SZ_HA)
#define SZ_RA    ((S_+1)*C_*B_)             // r history [t][k][b]
#define OFF_CT   (OFF_RA + SZ_RA)
#define SZ_CT    (H_*B_)                    // (unused now: c lives in registers)
#define OFF_M    (OFF_CT + SZ_CT)
#define SZ_M     (B_*N_*C_)                 // memory [b][n][c] (block-private)
#define OFF_WR   (OFF_M + SZ_M)
#define SZ_W     (B_*N_)                    // unused (layout stability)
#define OFF_WW   (OFF_WR + SZ_W)
#define OFF_BAR  (OFF_WW + SZ_W)
#define SZ_BAR   8192                       // arrive[256] + release[256], 64B-strided
#define OFF_WOT  (OFF_BAR + SZ_BAR)
#define SZ_WOT   ((H_+C_)*O_)               // W_out transposed [k][o]
#define OFF_WHH  (OFF_WOT + SZ_WOT)
#define SZ_WHH   ((P_*H_)/2)                // W_head as fp16 (137216 halves)

__device__ __forceinline__ float sigm(float x) { return 1.f / (1.f + expf(-x)); }
__device__ __forceinline__ float splus(float x) {
    return fmaxf(x, 0.f) + log1pf(expf(-fabsf(x)));  // stable softplus
}
__device__ __forceinline__ float wave_max(float v) {
    #pragma unroll
    for (int s = 1; s < 64; s <<= 1) v = fmaxf(v, __shfl_xor(v, s, 64));
    return v;
}
__device__ __forceinline__ float wave_sum(float v) {
    #pragma unroll
    for (int s = 1; s < 64; s <<= 1) v += __shfl_xor(v, s, 64);
    return v;
}

// HOT poll: dependent-FMA keep-alive between loads (NO s_sleep — rounds 4-9
// all slept and all landed at 35-55 us/step; the idle signature drives DVFS
// to a low DPM state, stretching every hop 4-5x). The asm keeps the chain live.
__device__ __forceinline__ void hotwait(unsigned* p, unsigned tgt) {
    float s = 1.f;
    while (__hip_atomic_load(p, __ATOMIC_RELAXED, __HIP_MEMORY_SCOPE_AGENT) < tgt) {
        #pragma unroll
        for (int d = 0; d < 16; ++d) s = fmaf(s, 1.0000001f, 1e-9f);
        asm volatile("" : "+v"(s));
    }
}

// ---- fence-free, contention-free grid barrier (round-6 topology) ----------
//   arrive[bi]  @ bar[bi*16]        : writer=block bi, reader=master lane bi
//   release[bi] @ bar[4096 + bi*16] : writer=master lane bi, reader=block bi
__device__ __forceinline__ void gbar(unsigned* bar, int bi, int tid, unsigned seq)
{
    __syncthreads();
    if (bi == NBLK - 1) {
        if (tid < NBLK - 1) hotwait(&bar[tid * 16], seq);
        __syncthreads();
        if (tid < NBLK)
            __hip_atomic_store(&bar[4096 + tid * 16], seq, __ATOMIC_RELAXED,
                               __HIP_MEMORY_SCOPE_AGENT);
        __syncthreads();
    } else {
        if (tid == 0) {
            asm volatile("s_waitcnt vmcnt(0) lgkmcnt(0)" ::: "memory");
            __hip_atomic_store(&bar[bi * 16], seq, __ATOMIC_RELAXED,
                               __HIP_MEMORY_SCOPE_AGENT);
            hotwait(&bar[4096 + bi * 16], seq);
        }
        __syncthreads();
    }
}

// ---------------- prep: transpose x & W_out, fp16 W_head, init state -------
__global__ __launch_bounds__(256)
void prep_kernel(const float* __restrict__ x, const float* __restrict__ Wout,
                 const float* __restrict__ Whead, float* __restrict__ ws)
{
    int g = blockIdx.x * 256 + threadIdx.x;
    if (g < SZ_XT) {                       // xT[t][k][b] = x[b][t][k]
        int b = g & 31, k = (g >> 5) & 255, t = g >> 13;
        ws[OFF_XT + g] = x[b * (S_*I_) + t * I_ + k];
        return;
    }
    g -= SZ_XT;
    if (g < SZ_WOT) {                      // WoT[k][o] = W_out[o][k]
        int o = g & 255, k = g >> 8;
        ws[OFF_WOT + g] = Wout[o * (H_ + C_) + k];
        return;
    }
    g -= SZ_WOT;
    if (g < HB)      { ws[OFF_HA + g] = 0.f;   return; }   // h slot 0
    g -= HB;
    if (g < C_*B_)   { ws[OFF_RA + g] = 0.f;   return; }   // r slot 0
    g -= C_*B_;
    if (g < SZ_CT)   { ws[OFF_CT + g] = 0.f;   return; }   // (unused)
    g -= SZ_CT;
    if (g < SZ_M)    { ws[OFF_M  + g] = 0.01f; return; }   // M
    g -= SZ_M;
    if (g < 2*SZ_W)  { ws[OFF_WR + g] = 0.f;   return; }   // unused slots
    g -= 2*SZ_W;
    if (g < SZ_BAR)  { ws[OFF_BAR + g] = 0.f;  return; }   // barrier slots
    g -= SZ_BAR;
    if (g < P_ * H_) {                     // W_head -> fp16 copy
        ((__half*)(ws + OFF_WHH))[g] = __float2half(Whead[g]);
        return;
    }
}

// ---------------- persistent sequential loop -------------------------------
// 256 blocks x 512 threads, 1 block/CU, 2 padded-slot barriers per step,
// HOT-polled. Block bi: ug = bi>>1 owns units [4ug,4ug+4) (16 gate rows in
// LDS), bh = bi&1 owns batches [16bh,16bh+16). Blocks 0..31 do ALL of phase B
// for batch bi; p, w_r, w_w in LDS; LSTM c in registers.
__global__ __launch_bounds__(512)
void ntm_loop(const float* __restrict__ Wih, const float* __restrict__ Whh,
              const float* __restrict__ bl,  const float* __restrict__ bhead,
              float* __restrict__ ws)
{
    float* xT  = ws + OFF_XT;
    float* hA  = ws + OFF_HA;
    float* rA  = ws + OFF_RA;
    float* Mem = ws + OFF_M;
    unsigned* bar = (unsigned*)(ws + OFF_BAR);
    const unsigned short* whH = (const unsigned short*)(ws + OFF_WHH);

    __shared__ float Wt[K_ * 18];     // gate rows transposed, stride 18
    __shared__ float p_lds[P_];
    __shared__ float sbuf[8];
    __shared__ float wtmp[128];
    __shared__ float wldsR[128];      // persistent w_r (blocks 0..31)
    __shared__ float wldsW[128];      // persistent w_w
    __shared__ float h_lds[H_];       // phase-B h staging

    const int tid = threadIdx.x;
    const int bi  = blockIdx.x;
    const int ug  = bi >> 1;
    const int bh  = bi & 1;

    // Load this block's 16 gate rows into LDS (once per launch).
    for (int idx = tid; idx < K_ * 16; idx += 512) {
        int rl = idx & 15, k = idx >> 4;
        int row = (rl & 3) * H_ + ug * 4 + (rl >> 2);
        float v = (k < I_ + C_) ? Wih[row * (I_ + C_) + k]
                                : Whh[row * H_ + (k - (I_ + C_))];
        Wt[k * 18 + rl] = v;
    }
    if (tid < N_) {                  // persistent addressing weights, w0 = e0
        wldsR[tid] = (tid == 0) ? 1.f : 0.f;
        wldsW[tid] = (tid == 0) ? 1.f : 0.f;
    }

    const int pair = tid >> 5;        // 0..15
    const int ks   = tid & 31;        // split-K lane
    const int rg   = pair >> 2;       // u_local 0..3
    const int bg   = pair & 3;        // batch quad 0..3
    const int b0   = bh * 16 + bg * 4;

    float cr[4] = {0.f, 0.f, 0.f, 0.f};   // LSTM c for (unit, b0..b0+3), ks==0 only
    unsigned seq = 0;

    for (int t = 0; t < S_; ++t) {
        // ------------- P1: gates GEMM + LSTM update -> h[t+1], c -------------
        {
            float acc[4][4] = {{0,0,0,0},{0,0,0,0},{0,0,0,0},{0,0,0,0}};
            const float* xs = xT + (size_t)t * I_ * B_;
            const float* rs = rA + (size_t)t * C_ * B_;
            const float* hs = hA + (size_t)t * HB;
            if (t == 0) __syncthreads();   // cover Wt / wlds staging
            #pragma unroll
            for (int i = 0; i < 26; ++i) {
                const int k = ks + (i << 5);
                const float* ap;
                if (i < 8)       ap = xs + k * B_ + b0;
                else if (i < 10) ap = rs + (k - I_) * B_ + b0;
                else             ap = hs + (k - I_ - C_) * B_ + b0;
                const float4 a   = *(const float4*)ap;
                const float2 w01 = *(const float2*)&Wt[k * 18 + (rg << 2)];
                const float2 w23 = *(const float2*)&Wt[k * 18 + (rg << 2) + 2];
                const float wv[4] = {w01.x, w01.y, w23.x, w23.y};
                const float av[4] = {a.x, a.y, a.z, a.w};
                #pragma unroll
                for (int j = 0; j < 4; ++j)
                    #pragma unroll
                    for (int bb = 0; bb < 4; ++bb)
                        acc[j][bb] += wv[j] * av[bb];
            }
            // split-K butterfly over 32 lanes
            #pragma unroll
            for (int j = 0; j < 4; ++j)
                #pragma unroll
                for (int bb = 0; bb < 4; ++bb) {
                    float v = acc[j][bb];
                    v += __shfl_xor(v, 16, 64);
                    v += __shfl_xor(v, 8, 64);
                    v += __shfl_xor(v, 4, 64);
                    v += __shfl_xor(v, 2, 64);
                    v += __shfl_xor(v, 1, 64);
                    acc[j][bb] = v;
                }
            if (ks == 0) {
                const int unit = ug * 4 + rg;
                #pragma unroll
                for (int bb = 0; bb < 4; ++bb) {
                    const int b = b0 + bb;
                    float gi = acc[0][bb] + bl[unit];
                    float gf = acc[1][bb] + bl[H_ + unit];
                    float gg = acc[2][bb] + bl[2 * H_ + unit];
                    float go = acc[3][bb] + bl[3 * H_ + unit];
                    float cN = sigm(gf) * cr[bb] + sigm(gi) * tanhf(gg);
                    float hN = sigm(go) * tanhf(cN);
                    cr[bb] = cN;                       // c in registers
                    __hip_atomic_store(&hA[(size_t)(t + 1) * HB + unit * B_ + b],
                                       hN, __ATOMIC_RELAXED,
                                       __HIP_MEMORY_SCOPE_AGENT);
                }
            }
        }
        gbar(bar, bi, tid, ++seq);

        // ---- Phase B (blocks 0..31): head GEMM + addressing + write + read ----
        if (bi < B_) {
            const int b = bi;
            float* Mb = Mem + (size_t)b * N_ * C_;
            const float* hs = hA + (size_t)(t + 1) * HB;

            // stage h[:,b] into LDS (agent loads: read coherence point)
            h_lds[tid] = __hip_atomic_load(&hs[tid * B_ + b], __ATOMIC_RELAXED,
                                           __HIP_MEMORY_SCOPE_AGENT);
            __syncthreads();

            // head GEMM (fp16 weights): p = W_head @ h + b_head, 2 thr/row
            {
                const int sub  = tid & 1;        // k-half
                const int row0 = tid >> 1;       // 0..255
                const float* hb = &h_lds[sub * 256];
                #pragma unroll
                for (int rep = 0; rep < 2; ++rep) {
                    const int row = (rep == 0) ? row0
                                  : ((row0 < P_ - 256) ? row0 + 256 : -1);
                    if (row >= 0) {
                        const unsigned short* wrow = whH + row * H_ + sub * 256;
                        float acc = 0.f;
                        #pragma unroll 4
                        for (int k2 = 0; k2 < 256; k2 += 8) {
                            float4 raw = *(const float4*)&wrow[k2];  // 8 halves
                            const __half2* hp = (const __half2*)&raw;
                            float2 f0 = __half22float2(hp[0]);
                            float2 f1 = __half22float2(hp[1]);
                            float2 f2 = __half22float2(hp[2]);
                            float2 f3 = __half22float2(hp[3]);
                            acc += f0.x * hb[k2]     + f0.y * hb[k2 + 1]
                                 + f1.x * hb[k2 + 2] + f1.y * hb[k2 + 3]
                                 + f2.x * hb[k2 + 4] + f2.y * hb[k2 + 5]
                                 + f3.x * hb[k2 + 6] + f3.y * hb[k2 + 7];
                        }
                        acc += __shfl_xor(acc, 1, 64);
                        if (sub == 0) p_lds[row] = acc + bhead[row];
                    }
                }
            }
            __syncthreads();

            // addressing: pass 0 read head (params at 0), pass 1 write head (70)
            for (int pass = 0; pass < 2; ++pass) {
                const int o = pass ? 70 : 0;
                float z = 0.f, beta = 0.f, gate = 0.f, s0 = 0.f, s1 = 0.f,
                      s2 = 0.f, gamma = 1.f;
                if (tid < N_) {
                    beta  = splus(p_lds[o + 64]);
                    gate  = sigm(p_lds[o + 65]);
                    float sa = p_lds[o + 66], sbv = p_lds[o + 67], sc = p_lds[o + 68];
                    float sm3 = fmaxf(sa, fmaxf(sbv, sc));
                    float ea = __expf(sa - sm3), eb = __expf(sbv - sm3),
                          ec = __expf(sc - sm3);
                    float es3 = ea + eb + ec;
                    s0 = ea / es3; s1 = eb / es3; s2 = ec / es3;
                    gamma = 1.f + splus(p_lds[o + 69]);
                    float kk = 0.f;
                    #pragma unroll 8
                    for (int c = 0; c < C_; ++c) { float kv = p_lds[o + c]; kk += kv * kv; }
                    const float knorm = sqrtf(kk) + EPSX;
                    float dot = 0.f, mm = 0.f;
                    #pragma unroll
                    for (int c = 0; c < C_; c += 4) {
                        float4 m4 = *(const float4*)&Mb[tid * C_ + c];
                        dot += m4.x * p_lds[o + c]     + m4.y * p_lds[o + c + 1]
                             + m4.z * p_lds[o + c + 2] + m4.w * p_lds[o + c + 3];
                        mm  += m4.x * m4.x + m4.y * m4.y + m4.z * m4.z + m4.w * m4.w;
                    }
                    z = beta * (dot / ((sqrtf(mm) + EPSX) * knorm));
                }
                // softmax over n=128 via wave shuffles (waves 0,1 fully active)
                float zm = wave_max(z);
                if (tid < N_ && (tid & 63) == 0) sbuf[tid >> 6] = zm;
                __syncthreads();
                const float zmax = fmaxf(sbuf[0], sbuf[1]);
                float ev = (tid < N_) ? __expf(z - zmax) : 0.f;
                float es = wave_sum(ev);
                if (tid < N_ && (tid & 63) == 0) sbuf[2 + (tid >> 6)] = es;
                __syncthreads();
                const float esum = sbuf[2] + sbuf[3];
                if (tid < N_) {
                    float wc = ev / esum;
                    float wprev_v = pass ? wldsW[tid] : wldsR[tid];
                    wtmp[tid] = gate * wc + (1.f - gate) * wprev_v;
                }
                __syncthreads();
                float wp = 0.f;
                if (tid < N_) {
                    float wsft = s0 * wtmp[(tid + 1) & (N_-1)] + s1 * wtmp[tid]
                               + s2 * wtmp[(tid - 1) & (N_-1)];
                    wp = __powf(wsft + EPSX, gamma);
                }
                float ps = wave_sum(wp);
                if (tid < N_ && (tid & 63) == 0) sbuf[4 + (tid >> 6)] = ps;
                __syncthreads();
                const float psum = sbuf[4] + sbuf[5];
                if (tid < N_) {
                    float wn = wp / psum;
                    if (pass) wldsW[tid] = wn; else wldsR[tid] = wn;
                }
                __syncthreads();
            }

            // M = M*(1 - w_w e) + w_w a   (private)
            for (int idx = tid; idx < (N_ * C_) / 4; idx += 512) {
                const int n = idx >> 4;
                const int c = (idx & 15) << 2;
                const float wwn = wldsW[n];
                float4 m4 = *(float4*)&Mb[n * C_ + c];
                m4.x = m4.x * (1.f - wwn * sigm(p_lds[140 + c]))     + wwn * p_lds[204 + c];
                m4.y = m4.y * (1.f - wwn * sigm(p_lds[140 + c + 1])) + wwn * p_lds[204 + c + 1];
                m4.z = m4.z * (1.f - wwn * sigm(p_lds[140 + c + 2])) + wwn * p_lds[204 + c + 2];
                m4.w = m4.w * (1.f - wwn * sigm(p_lds[140 + c + 3])) + wwn * p_lds[204 + c + 3];
                *(float4*)&Mb[n * C_ + c] = m4;
            }
            __syncthreads();

            // r = w_r @ M_new  -> publish to L3
            {
                const int c = tid >> 3, ns = tid & 7;
                float acc = 0.f;
                #pragma unroll
                for (int i = 0; i < 16; ++i) {
                    const int n = ns + 8 * i;
                    acc += wldsR[n] * Mb[n * C_ + c];
                }
                acc += __shfl_xor(acc, 4, 64);
                acc += __shfl_xor(acc, 2, 64);
                acc += __shfl_xor(acc, 1, 64);
                if (ns == 0)
                    __hip_atomic_store(&rA[(size_t)(t + 1) * C_ * B_ + c * B_ + b],
                                       acc, __ATOMIC_RELAXED,
                                       __HIP_MEMORY_SCOPE_AGENT);
            }
        }
        gbar(bar, bi, tid, ++seq);
    }
}

// ---------------- final output GEMM ----------------
__global__ __launch_bounds__(256)
void out_kernel(const float* __restrict__ ws, const float* __restrict__ bout,
                float* __restrict__ out)
{
    __shared__ float actL[(H_ + C_) * 16];   // 36,864 B
    const float* hA  = ws + OFF_HA;
    const float* rA  = ws + OFF_RA;
    const float* WoT = ws + OFF_WOT;
    const int t   = blockIdx.x >> 1;
    const int bh  = blockIdx.x & 1;
    const int tid = threadIdx.x;

    for (int idx = tid; idx < (H_ + C_) * 16; idx += 256) {
        const int k = idx >> 4, bl2 = idx & 15, b = bh * 16 + bl2;
        float v = (k < H_) ? hA[(size_t)(t + 1) * HB + k * B_ + b]
                           : rA[(size_t)(t + 1) * C_ * B_ + (k - H_) * B_ + b];
        actL[k * 16 + bl2] = v;
    }
    __syncthreads();

    const int ot = tid & 63, bt = tid >> 6;
    const int o0 = ot * 4, bl0 = bt * 4;
    float acc[4][4] = {{0,0,0,0},{0,0,0,0},{0,0,0,0},{0,0,0,0}};
    for (int k = 0; k < H_ + C_; ++k) {
        const float4 w4 = *(const float4*)&WoT[k * O_ + o0];
        const float4 a4 = *(const float4*)&actL[k * 16 + bl0];
        const float wv[4] = {w4.x, w4.y, w4.z, w4.w};
        const float av[4] = {a4.x, a4.y, a4.z, a4.w};
        #pragma unroll
        for (int j = 0; j < 4; ++j)
            #pragma unroll
            for (int bb = 0; bb < 4; ++bb)
                acc[j][bb] += wv[j] * av[bb];
    }
    const float4 bo = *(const float4*)&bout[o0];
    #pragma unroll
    for (int bb = 0; bb < 4; ++bb) {
        const int b = bh * 16 + bl0 + bb;
        float4 res;
        res.x = acc[0][bb] + bo.x;
        res.y = acc[1][bb] + bo.y;
        res.z = acc[2][bb] + bo.z;
        res.w = acc[3][bb] + bo.w;
        *(float4*)&out[((size_t)b * S_ + t) * O_ + o0] = res;
    }
}

extern "C" void kernel_launch(void* const* d_in, const int* in_sizes, int n_in,
                              void* d_out, int out_size, void* d_ws, size_t ws_size,
                              hipStream_t stream)
{
    const float* x    = (const float*)d_in[0];
    const float* Wih  = (const float*)d_in[1];
    const float* Whh  = (const float*)d_in[2];
    const float* bl   = (const float*)d_in[3];
    const float* Whd  = (const float*)d_in[4];
    const float* bhd  = (const float*)d_in[5];
    const float* Wout = (const float*)d_in[6];
    const float* bout = (const float*)d_in[7];
    float* ws  = (float*)d_ws;    // needs 29.4 MB
    float* out = (float*)d_out;

    prep_kernel<<<10529, 256, 0, stream>>>(x, Wout, Whd, ws);

    void* args[] = { (void*)&Wih, (void*)&Whh, (void*)&bl,
                     (void*)&bhd, (void*)&ws };
    (void)hipLaunchCooperativeKernel((void*)ntm_loop, dim3(256), dim3(512), args, 0, stream);

    out_kernel<<<512, 256, 0, stream>>>(ws, bout, out);
}

// Round 11
// 8364.250 us; speedup vs baseline: 1.6261x; 1.0330x over previous
//
#include <hip/hip_runtime.h>
#include <hip/hip_fp16.h>
#include <math.h>

// Problem dims
#define B_  32
#define S_  256
#define I_  256
#define H_  512
#define N_  128
#define C_  64
#define O_  256
#define P_  268          // 4*C + 12
#define K_  832          // I + C + H
#define HB  (H_*B_)      // 16384
#define EPSX 1e-8f
#define NBLK 256

// Workspace layout (float offsets). Total 7,345,152 floats = 29.4 MB.
#define OFF_XT   0
#define SZ_XT    (S_*I_*B_)                 // x transposed [t][k][b]
#define OFF_HA   (OFF_XT + SZ_XT)
#define SZ_HA    ((S_+1)*H_*B_)             // h history [t][k][b]
#define OFF_RA   (OFF_HA + SZ_HA)
#define SZ_RA    ((S_+1)*C_*B_)             // r history [t][k][b]
#define OFF_CT   (OFF_RA + SZ_RA)
#define SZ_CT    (H_*B_)                    // (unused: c lives in registers)
#define OFF_M    (OFF_CT + SZ_CT)
#define SZ_M     (B_*N_*C_)                 // memory [b][n][c] (block-private)
#define OFF_WR   (OFF_M + SZ_M)
#define SZ_W     (B_*N_)                    // unused (layout stability)
#define OFF_WW   (OFF_WR + SZ_W)
#define OFF_BAR  (OFF_WW + SZ_W)
#define SZ_BAR   8192                       // arrive[256] + release[256], 64B-strided
#define OFF_WOT  (OFF_BAR + SZ_BAR)
#define SZ_WOT   ((H_+C_)*O_)               // W_out transposed [k][o]
#define OFF_WHH  (OFF_WOT + SZ_WOT)
#define SZ_WHH   ((P_*H_)/2)                // W_head as fp16 (137216 halves)

__device__ __forceinline__ float sigm(float x) { return 1.f / (1.f + expf(-x)); }
__device__ __forceinline__ float splus(float x) {
    return fmaxf(x, 0.f) + log1pf(expf(-fabsf(x)));  // stable softplus
}
__device__ __forceinline__ float wave_max(float v) {
    #pragma unroll
    for (int s = 1; s < 64; s <<= 1) v = fmaxf(v, __shfl_xor(v, s, 64));
    return v;
}
__device__ __forceinline__ float wave_sum(float v) {
    #pragma unroll
    for (int s = 1; s < 64; s <<= 1) v += __shfl_xor(v, s, 64);
    return v;
}

// Keep-alive: dependent FMA chain, defeats DCE via inline-asm tie.
__device__ __forceinline__ void junk16(float& s) {
    #pragma unroll
    for (int d = 0; d < 16; ++d) s = fmaf(s, 1.0000001f, 1e-9f);
    asm volatile("" : "+v"(s));
}

// HOT poll (single lane): dependent-FMA between agent-scope loads.
__device__ __forceinline__ void hotwait(unsigned* p, unsigned tgt) {
    float s = 1.f;
    while (__hip_atomic_load(p, __ATOMIC_RELAXED, __HIP_MEMORY_SCOPE_AGENT) < tgt)
        junk16(s);
}

// ---- contention-free grid barrier with ALL-LANE busy wait -----------------
// Round-10 post-mortem: VALUBusy 16% at "600 MHz-equivalent" step times —
// the chip downclocks because 99.8% of lanes idle in s_barrier during waits.
// Fix: non-master blocks spin ALL 512 lanes on an LDS mirror flag running
// dense FMA junk (full-chip FP32 activity -> DPM holds boost); tid0 forwards
// the global release line into the LDS flag.
//   arrive[bi]  @ bar[bi*16]        : writer=block bi, reader=master lane bi
//   release[bi] @ bar[4096 + bi*16] : writer=master lane bi, reader=block bi
__device__ __forceinline__ void gbar(unsigned* bar, volatile unsigned* ldsf,
                                     int bi, int tid, unsigned seq)
{
    __syncthreads();
    if (bi == NBLK - 1) {
        if (tid < NBLK - 1) hotwait(&bar[tid * 16], seq);
        else {
            float s = 1.f;  // non-polling master lanes stay hot too
            junk16(s);
        }
        __syncthreads();
        if (tid < NBLK)
            __hip_atomic_store(&bar[4096 + tid * 16], seq, __ATOMIC_RELAXED,
                               __HIP_MEMORY_SCOPE_AGENT);
        __syncthreads();
    } else {
        if (tid == 0) {
            asm volatile("s_waitcnt vmcnt(0) lgkmcnt(0)" ::: "memory");
            __hip_atomic_store(&bar[bi * 16], seq, __ATOMIC_RELAXED,
                               __HIP_MEMORY_SCOPE_AGENT);
        }
        // ALL lanes busy-spin on the LDS mirror; tid0 forwards global->LDS
        float s = (float)(tid + 1);
        for (;;) {
            if (*ldsf >= seq) break;
            if (tid == 0 &&
                __hip_atomic_load(&bar[4096 + bi * 16], __ATOMIC_RELAXED,
                                  __HIP_MEMORY_SCOPE_AGENT) >= seq)
                *ldsf = seq;
            junk16(s);
        }
        __syncthreads();   // reconverge (all lanes present -> cheap)
    }
}

// ---------------- prep: transpose x & W_out, fp16 W_head, init state -------
__global__ __launch_bounds__(256)
void prep_kernel(const float* __restrict__ x, const float* __restrict__ Wout,
                 const float* __restrict__ Whead, float* __restrict__ ws)
{
    int g = blockIdx.x * 256 + threadIdx.x;
    if (g < SZ_XT) {                       // xT[t][k][b] = x[b][t][k]
        int b = g & 31, k = (g >> 5) & 255, t = g >> 13;
        ws[OFF_XT + g] = x[b * (S_*I_) + t * I_ + k];
        return;
    }
    g -= SZ_XT;
    if (g < SZ_WOT) {                      // WoT[k][o] = W_out[o][k]
        int o = g & 255, k = g >> 8;
        ws[OFF_WOT + g] = Wout[o * (H_ + C_) + k];
        return;
    }
    g -= SZ_WOT;
    if (g < HB)      { ws[OFF_HA + g] = 0.f;   return; }   // h slot 0
    g -= HB;
    if (g < C_*B_)   { ws[OFF_RA + g] = 0.f;   return; }   // r slot 0
    g -= C_*B_;
    if (g < SZ_CT)   { ws[OFF_CT + g] = 0.f;   return; }   // (unused)
    g -= SZ_CT;
    if (g < SZ_M)    { ws[OFF_M  + g] = 0.01f; return; }   // M
    g -= SZ_M;
    if (g < 2*SZ_W)  { ws[OFF_WR + g] = 0.f;   return; }   // unused slots
    g -= 2*SZ_W;
    if (g < SZ_BAR)  { ws[OFF_BAR + g] = 0.f;  return; }   // barrier slots
    g -= SZ_BAR;
    if (g < P_ * H_) {                     // W_head -> fp16 copy
        ((__half*)(ws + OFF_WHH))[g] = __float2half(Whead[g]);
        return;
    }
}

// ---------------- persistent sequential loop -------------------------------
// 256 blocks x 512 threads, 1 block/CU, 2 padded-slot barriers per step with
// all-lane busy waits. Block bi: ug = bi>>1 owns units [4ug,4ug+4), bh = bi&1
// owns batches [16bh,16bh+16). Blocks 0..31 do ALL of phase B for batch bi;
// p, w_r, w_w in LDS; LSTM c in registers.
__global__ __launch_bounds__(512)
void ntm_loop(const float* __restrict__ Wih, const float* __restrict__ Whh,
              const float* __restrict__ bl,  const float* __restrict__ bhead,
              float* __restrict__ ws)
{
    float* xT  = ws + OFF_XT;
    float* hA  = ws + OFF_HA;
    float* rA  = ws + OFF_RA;
    float* Mem = ws + OFF_M;
    unsigned* bar = (unsigned*)(ws + OFF_BAR);
    const unsigned short* whH = (const unsigned short*)(ws + OFF_WHH);

    __shared__ float Wt[K_ * 18];     // gate rows transposed, stride 18
    __shared__ float p_lds[P_];
    __shared__ float sbuf[8];
    __shared__ float wtmp[128];
    __shared__ float wldsR[128];      // persistent w_r (blocks 0..31)
    __shared__ float wldsW[128];      // persistent w_w
    __shared__ float h_lds[H_];       // phase-B h staging
    __shared__ unsigned relf;         // LDS mirror of this block's release line

    const int tid = threadIdx.x;
    const int bi  = blockIdx.x;
    const int ug  = bi >> 1;
    const int bh  = bi & 1;

    if (tid == 0) relf = 0;

    // Load this block's 16 gate rows into LDS (once per launch).
    for (int idx = tid; idx < K_ * 16; idx += 512) {
        int rl = idx & 15, k = idx >> 4;
        int row = (rl & 3) * H_ + ug * 4 + (rl >> 2);
        float v = (k < I_ + C_) ? Wih[row * (I_ + C_) + k]
                                : Whh[row * H_ + (k - (I_ + C_))];
        Wt[k * 18 + rl] = v;
    }
    if (tid < N_) {                  // persistent addressing weights, w0 = e0
        wldsR[tid] = (tid == 0) ? 1.f : 0.f;
        wldsW[tid] = (tid == 0) ? 1.f : 0.f;
    }

    const int pair = tid >> 5;        // 0..15
    const int ks   = tid & 31;        // split-K lane
    const int rg   = pair >> 2;       // u_local 0..3
    const int bg   = pair & 3;        // batch quad 0..3
    const int b0   = bh * 16 + bg * 4;

    float cr[4] = {0.f, 0.f, 0.f, 0.f};   // LSTM c (ks==0 lanes only)
    unsigned seq = 0;

    for (int t = 0; t < S_; ++t) {
        // ------------- P1: gates GEMM + LSTM update -> h[t+1], c -------------
        {
            float acc[4][4] = {{0,0,0,0},{0,0,0,0},{0,0,0,0},{0,0,0,0}};
            const float* xs = xT + (size_t)t * I_ * B_;
            const float* rs = rA + (size_t)t * C_ * B_;
            const float* hs = hA + (size_t)t * HB;
            if (t == 0) __syncthreads();   // cover Wt / wlds / relf staging
            #pragma unroll
            for (int i = 0; i < 26; ++i) {
                const int k = ks + (i << 5);
                const float* ap;
                if (i < 8)       ap = xs + k * B_ + b0;
                else if (i < 10) ap = rs + (k - I_) * B_ + b0;
                else             ap = hs + (k - I_ - C_) * B_ + b0;
                const float4 a   = *(const float4*)ap;
                const float2 w01 = *(const float2*)&Wt[k * 18 + (rg << 2)];
                const float2 w23 = *(const float2*)&Wt[k * 18 + (rg << 2) + 2];
                const float wv[4] = {w01.x, w01.y, w23.x, w23.y};
                const float av[4] = {a.x, a.y, a.z, a.w};
                #pragma unroll
                for (int j = 0; j < 4; ++j)
                    #pragma unroll
                    for (int bb = 0; bb < 4; ++bb)
                        acc[j][bb] += wv[j] * av[bb];
            }
            // split-K butterfly over 32 lanes
            #pragma unroll
            for (int j = 0; j < 4; ++j)
                #pragma unroll
                for (int bb = 0; bb < 4; ++bb) {
                    float v = acc[j][bb];
                    v += __shfl_xor(v, 16, 64);
                    v += __shfl_xor(v, 8, 64);
                    v += __shfl_xor(v, 4, 64);
                    v += __shfl_xor(v, 2, 64);
                    v += __shfl_xor(v, 1, 64);
                    acc[j][bb] = v;
                }
            if (ks == 0) {
                const int unit = ug * 4 + rg;
                #pragma unroll
                for (int bb = 0; bb < 4; ++bb) {
                    const int b = b0 + bb;
                    float gi = acc[0][bb] + bl[unit];
                    float gf = acc[1][bb] + bl[H_ + unit];
                    float gg = acc[2][bb] + bl[2 * H_ + unit];
                    float go = acc[3][bb] + bl[3 * H_ + unit];
                    float cN = sigm(gf) * cr[bb] + sigm(gi) * tanhf(gg);
                    float hN = sigm(go) * tanhf(cN);
                    cr[bb] = cN;                       // c in registers
                    __hip_atomic_store(&hA[(size_t)(t + 1) * HB + unit * B_ + b],
                                       hN, __ATOMIC_RELAXED,
                                       __HIP_MEMORY_SCOPE_AGENT);
                }
            }
        }
        gbar(bar, &relf, bi, tid, ++seq);

        // ---- Phase B (blocks 0..31): head GEMM + addressing + write + read ----
        if (bi < B_) {
            const int b = bi;
            float* Mb = Mem + (size_t)b * N_ * C_;
            const float* hs = hA + (size_t)(t + 1) * HB;

            // stage h[:,b] into LDS (agent loads: read coherence point)
            h_lds[tid] = __hip_atomic_load(&hs[tid * B_ + b], __ATOMIC_RELAXED,
                                           __HIP_MEMORY_SCOPE_AGENT);
            __syncthreads();

            // head GEMM (fp16 weights): p = W_head @ h + b_head, 2 thr/row
            {
                const int sub  = tid & 1;        // k-half
                const int row0 = tid >> 1;       // 0..255
                const float* hb = &h_lds[sub * 256];
                #pragma unroll
                for (int rep = 0; rep < 2; ++rep) {
                    const int row = (rep == 0) ? row0
                                  : ((row0 < P_ - 256) ? row0 + 256 : -1);
                    if (row >= 0) {
                        const unsigned short* wrow = whH + row * H_ + sub * 256;
                        float acc = 0.f;
                        #pragma unroll 4
                        for (int k2 = 0; k2 < 256; k2 += 8) {
                            float4 raw = *(const float4*)&wrow[k2];  // 8 halves
                            const __half2* hp = (const __half2*)&raw;
                            float2 f0 = __half22float2(hp[0]);
                            float2 f1 = __half22float2(hp[1]);
                            float2 f2 = __half22float2(hp[2]);
                            float2 f3 = __half22float2(hp[3]);
                            acc += f0.x * hb[k2]     + f0.y * hb[k2 + 1]
                                 + f1.x * hb[k2 + 2] + f1.y * hb[k2 + 3]
                                 + f2.x * hb[k2 + 4] + f2.y * hb[k2 + 5]
                                 + f3.x * hb[k2 + 6] + f3.y * hb[k2 + 7];
                        }
                        acc += __shfl_xor(acc, 1, 64);
                        if (sub == 0) p_lds[row] = acc + bhead[row];
                    }
                }
            }
            __syncthreads();

            // addressing: pass 0 read head (params at 0), pass 1 write head (70)
            for (int pass = 0; pass < 2; ++pass) {
                const int o = pass ? 70 : 0;
                float z = 0.f, beta = 0.f, gate = 0.f, s0 = 0.f, s1 = 0.f,
                      s2 = 0.f, gamma = 1.f;
                if (tid < N_) {
                    beta  = splus(p_lds[o + 64]);
                    gate  = sigm(p_lds[o + 65]);
                    float sa = p_lds[o + 66], sbv = p_lds[o + 67], sc = p_lds[o + 68];
                    float sm3 = fmaxf(sa, fmaxf(sbv, sc));
                    float ea = __expf(sa - sm3), eb = __expf(sbv - sm3),
                          ec = __expf(sc - sm3);
                    float es3 = ea + eb + ec;
                    s0 = ea / es3; s1 = eb / es3; s2 = ec / es3;
                    gamma = 1.f + splus(p_lds[o + 69]);
                    float kk = 0.f;
                    #pragma unroll 8
                    for (int c = 0; c < C_; ++c) { float kv = p_lds[o + c]; kk += kv * kv; }
                    const float knorm = sqrtf(kk) + EPSX;
                    float dot = 0.f, mm = 0.f;
                    #pragma unroll
                    for (int c = 0; c < C_; c += 4) {
                        float4 m4 = *(const float4*)&Mb[tid * C_ + c];
                        dot += m4.x * p_lds[o + c]     + m4.y * p_lds[o + c + 1]
                             + m4.z * p_lds[o + c + 2] + m4.w * p_lds[o + c + 3];
                        mm  += m4.x * m4.x + m4.y * m4.y + m4.z * m4.z + m4.w * m4.w;
                    }
                    z = beta * (dot / ((sqrtf(mm) + EPSX) * knorm));
                }
                // softmax over n=128 via wave shuffles (waves 0,1 fully active)
                float zm = wave_max(z);
                if (tid < N_ && (tid & 63) == 0) sbuf[tid >> 6] = zm;
                __syncthreads();
                const float zmax = fmaxf(sbuf[0], sbuf[1]);
                float ev = (tid < N_) ? __expf(z - zmax) : 0.f;
                float es = wave_sum(ev);
                if (tid < N_ && (tid & 63) == 0) sbuf[2 + (tid >> 6)] = es;
                __syncthreads();
                const float esum = sbuf[2] + sbuf[3];
                if (tid < N_) {
                    float wc = ev / esum;
                    float wprev_v = pass ? wldsW[tid] : wldsR[tid];
                    wtmp[tid] = gate * wc + (1.f - gate) * wprev_v;
                }
                __syncthreads();
                float wp = 0.f;
                if (tid < N_) {
                    float wsft = s0 * wtmp[(tid + 1) & (N_-1)] + s1 * wtmp[tid]
                               + s2 * wtmp[(tid - 1) & (N_-1)];
                    wp = __powf(wsft + EPSX, gamma);
                }
                float ps = wave_sum(wp);
                if (tid < N_ && (tid & 63) == 0) sbuf[4 + (tid >> 6)] = ps;
                __syncthreads();
                const float psum = sbuf[4] + sbuf[5];
                if (tid < N_) {
                    float wn = wp / psum;
                    if (pass) wldsW[tid] = wn; else wldsR[tid] = wn;
                }
                __syncthreads();
            }

            // M = M*(1 - w_w e) + w_w a   (private)
            for (int idx = tid; idx < (N_ * C_) / 4; idx += 512) {
                const int n = idx >> 4;
                const int c = (idx & 15) << 2;
                const float wwn = wldsW[n];
                float4 m4 = *(float4*)&Mb[n * C_ + c];
                m4.x = m4.x * (1.f - wwn * sigm(p_lds[140 + c]))     + wwn * p_lds[204 + c];
                m4.y = m4.y * (1.f - wwn * sigm(p_lds[140 + c + 1])) + wwn * p_lds[204 + c + 1];
                m4.z = m4.z * (1.f - wwn * sigm(p_lds[140 + c + 2])) + wwn * p_lds[204 + c + 2];
                m4.w = m4.w * (1.f - wwn * sigm(p_lds[140 + c + 3])) + wwn * p_lds[204 + c + 3];
                *(float4*)&Mb[n * C_ + c] = m4;
            }
            __syncthreads();

            // r = w_r @ M_new  -> publish to L3
            {
                const int c = tid >> 3, ns = tid & 7;
                float acc = 0.f;
                #pragma unroll
                for (int i = 0; i < 16; ++i) {
                    const int n = ns + 8 * i;
                    acc += wldsR[n] * Mb[n * C_ + c];
                }
                acc += __shfl_xor(acc, 4, 64);
                acc += __shfl_xor(acc, 2, 64);
                acc += __shfl_xor(acc, 1, 64);
                if (ns == 0)
                    __hip_atomic_store(&rA[(size_t)(t + 1) * C_ * B_ + c * B_ + b],
                                       acc, __ATOMIC_RELAXED,
                                       __HIP_MEMORY_SCOPE_AGENT);
            }
        }
        gbar(bar, &relf, bi, tid, ++seq);
    }
}

// ---------------- final output GEMM ----------------
__global__ __launch_bounds__(256)
void out_kernel(const float* __restrict__ ws, const float* __restrict__ bout,
                float* __restrict__ out)
{
    __shared__ float actL[(H_ + C_) * 16];   // 36,864 B
    const float* hA  = ws + OFF_HA;
    const float* rA  = ws + OFF_RA;
    const float* WoT = ws + OFF_WOT;
    const int t   = blockIdx.x >> 1;
    const int bh  = blockIdx.x & 1;
    const int tid = threadIdx.x;

    for (int idx = tid; idx < (H_ + C_) * 16; idx += 256) {
        const int k = idx >> 4, bl2 = idx & 15, b = bh * 16 + bl2;
        float v = (k < H_) ? hA[(size_t)(t + 1) * HB + k * B_ + b]
                           : rA[(size_t)(t + 1) * C_ * B_ + (k - H_) * B_ + b];
        actL[k * 16 + bl2] = v;
    }
    __syncthreads();

    const int ot = tid & 63, bt = tid >> 6;
    const int o0 = ot * 4, bl0 = bt * 4;
    float acc[4][4] = {{0,0,0,0},{0,0,0,0},{0,0,0,0},{0,0,0,0}};
    for (int k = 0; k < H_ + C_; ++k) {
        const float4 w4 = *(const float4*)&WoT[k * O_ + o0];
        const float4 a4 = *(const float4*)&actL[k * 16 + bl0];
        const float wv[4] = {w4.x, w4.y, w4.z, w4.w};
        const float av[4] = {a4.x, a4.y, a4.z, a4.w};
        #pragma unroll
        for (int j = 0; j < 4; ++j)
            #pragma unroll
            for (int bb = 0; bb < 4; ++bb)
                acc[j][bb] += wv[j] * av[bb];
    }
    const float4 bo = *(const float4*)&bout[o0];
    #pragma unroll
    for (int bb = 0; bb < 4; ++bb) {
        const int b = bh * 16 + bl0 + bb;
        float4 res;
        res.x = acc[0][bb] + bo.x;
        res.y = acc[1][bb] + bo.y;
        res.z = acc[2][bb] + bo.z;
        res.w = acc[3][bb] + bo.w;
        *(float4*)&out[((size_t)b * S_ + t) * O_ + o0] = res;
    }
}

extern "C" void kernel_launch(void* const* d_in, const int* in_sizes, int n_in,
                              void* d_out, int out_size, void* d_ws, size_t ws_size,
                              hipStream_t stream)
{
    const float* x    = (const float*)d_in[0];
    const float* Wih  = (const float*)d_in[1];
    const float* Whh  = (const float*)d_in[2];
    const float* bl   = (const float*)d_in[3];
    const float* Whd  = (const float*)d_in[4];
    const float* bhd  = (const float*)d_in[5];
    const float* Wout = (const float*)d_in[6];
    const float* bout = (const float*)d_in[7];
    float* ws  = (float*)d_ws;    // needs 29.4 MB
    float* out = (float*)d_out;

    prep_kernel<<<10529, 256, 0, stream>>>(x, Wout, Whd, ws);

    void* args[] = { (void*)&Wih, (void*)&Whh, (void*)&bl,
                     (void*)&bhd, (void*)&ws };
    (void)hipLaunchCooperativeKernel((void*)ntm_loop, dim3(256), dim3(512), args, 0, stream);

    out_kernel<<<512, 256, 0, stream>>>(ws, bout, out);
}